// Round 5
// baseline (265.130 us; speedup 1.0000x reference)
//
#include <hip/hip_runtime.h>

#define N_NODES 100000
#define N_EDGES 2000000

typedef __bf16 bf16x8 __attribute__((ext_vector_type(8)));
typedef float f32x4 __attribute__((ext_vector_type(4)));

__device__ __forceinline__ unsigned f2bf_rne(float f) {
  unsigned u = __builtin_bit_cast(unsigned, f);
  u += 0x7FFFu + ((u >> 16) & 1u);
  return u >> 16;
}

// Pack two NON-NEGATIVE f32 into bf16x2, round-half-up (3 VALU for 2 elems).
__device__ __forceinline__ unsigned pack_rhu(float lo, float hi) {
  unsigned ulo = __builtin_bit_cast(unsigned, lo) + 0x8000u;
  unsigned uhi = __builtin_bit_cast(unsigned, hi) + 0x8000u;
  return __builtin_amdgcn_perm(uhi, ulo, 0x07060302u);
}

// |a-b| on a packed bf16 pair -> packed bf16 pair (~7 VALU).
__device__ __forceinline__ unsigned absdiff_pack(unsigned a, unsigned b) {
  float alo = __builtin_bit_cast(float, a << 16);
  float ahi = __builtin_bit_cast(float, a & 0xFFFF0000u);
  float blo = __builtin_bit_cast(float, b << 16);
  float bhi = __builtin_bit_cast(float, b & 0xFFFF0000u);
  return pack_rhu(fabsf(alo - blo), fabsf(ahi - bhi));
}

// ---------------------------------------------------------------------------
// Fused node MLP via MFMA, grid-stride (unchanged from round 4 — its
// arithmetic floor is ~5us; the constant ~80us gap across radically different
// node configs in rounds 3/4 points to fixed harness overhead, not this
// kernel).
// ---------------------------------------------------------------------------
__global__ __launch_bounds__(64, 1) void node_mfma_kernel(
    const float* __restrict__ X, const float* __restrict__ W1,
    const float* __restrict__ b1, const float* __restrict__ W2,
    const float* __restrict__ b2, unsigned short* __restrict__ H) {
  const int lane = threadIdx.x;
  const int l15 = lane & 15;
  const int quad = lane >> 4;

  float w1v[2][4][8], b1v[2][8];
#pragma unroll
  for (int c = 0; c < 2; ++c)
#pragma unroll
    for (int j = 0; j < 8; ++j) {
      int col = c * 32 + quad * 8 + j;
      b1v[c][j] = b1[col];
#pragma unroll
      for (int d = 0; d < 4; ++d) w1v[c][d][j] = W1[d * 64 + col];
    }

  uint4 afr[2][4];
#pragma unroll
  for (int c = 0; c < 2; ++c)
#pragma unroll
    for (int mt = 0; mt < 4; ++mt) {
      unsigned w[4];
#pragma unroll
      for (int p = 0; p < 4; ++p) {
        int k = c * 32 + quad * 8 + 2 * p;
        unsigned lo = f2bf_rne(W2[k * 64 + mt * 16 + l15]);
        unsigned hi = f2bf_rne(W2[(k + 1) * 64 + mt * 16 + l15]);
        w[p] = lo | (hi << 16);
      }
      afr[c][mt] = make_uint4(w[0], w[1], w[2], w[3]);
    }
  float b2v[16];
#pragma unroll
  for (int mt = 0; mt < 4; ++mt)
#pragma unroll
    for (int r = 0; r < 4; ++r) b2v[mt * 4 + r] = b2[mt * 16 + quad * 4 + r];

  const int ntiles = N_NODES / 16;  // 6250
  for (int tile = blockIdx.x; tile < ntiles; tile += gridDim.x) {
    float4 xv = ((const float4*)X)[tile * 16 + l15];

    uint4 bfr[2];
#pragma unroll
    for (int c = 0; c < 2; ++c) {
      unsigned w[4];
#pragma unroll
      for (int p = 0; p < 4; ++p) {
        float h0 = fmaxf(b1v[c][2 * p] + xv.x * w1v[c][0][2 * p] +
                             xv.y * w1v[c][1][2 * p] + xv.z * w1v[c][2][2 * p] +
                             xv.w * w1v[c][3][2 * p],
                         0.f);
        float h1 = fmaxf(b1v[c][2 * p + 1] + xv.x * w1v[c][0][2 * p + 1] +
                             xv.y * w1v[c][1][2 * p + 1] +
                             xv.z * w1v[c][2][2 * p + 1] +
                             xv.w * w1v[c][3][2 * p + 1],
                         0.f);
        w[p] = pack_rhu(h0, h1);
      }
      bfr[c] = make_uint4(w[0], w[1], w[2], w[3]);
    }

    f32x4 acc[4];
#pragma unroll
    for (int mt = 0; mt < 4; ++mt) acc[mt] = (f32x4){0.f, 0.f, 0.f, 0.f};
#pragma unroll
    for (int c = 0; c < 2; ++c)
#pragma unroll
      for (int mt = 0; mt < 4; ++mt)
        acc[mt] = __builtin_amdgcn_mfma_f32_16x16x32_bf16(
            __builtin_bit_cast(bf16x8, afr[c][mt]),
            __builtin_bit_cast(bf16x8, bfr[c]), acc[mt], 0, 0, 0);

    unsigned short* hrow = H + (tile * 16 + l15) * 64;
#pragma unroll
    for (int mt = 0; mt < 4; ++mt) {
      unsigned lo = pack_rhu(fmaxf(acc[mt][0] + b2v[mt * 4 + 0], 0.f),
                             fmaxf(acc[mt][1] + b2v[mt * 4 + 1], 0.f));
      unsigned hi = pack_rhu(fmaxf(acc[mt][2] + b2v[mt * 4 + 2], 0.f),
                             fmaxf(acc[mt][3] + b2v[mt * 4 + 3], 0.f));
      *(uint2*)(hrow + mt * 16 + quad * 4) = make_uint2(lo, hi);
    }
  }
}

// ---------------------------------------------------------------------------
// Edge MLP, occupancy-first. We1^T A-frags live in LDS (24 KB) and are
// re-read per tile via ds_read_b128 (24/tile, conflict-free: contiguous
// 16B/lane). VGPR drops from ~200 (round-3/4 register-resident weights ->
// 2 waves/SIMD, 40% idle) to ~130 -> 3-4 waves/SIMD; latency hidden by TLP.
// launch_bounds(256,3): cap ~170, comfortable margin -> no spill (round-2's
// (256,4) cap forced a 64-reg allocation with 54MB of scratch traffic that
// thrashed L2 — the tripwire for that failure mode is WRITE_SIZE >> 8MB).
// 1-deep gather prefetch (2-deep was a no-op in round 4: the register
// rotation forces the vmcnt wait in the same iteration anyway).
// ---------------------------------------------------------------------------
__global__ __launch_bounds__(256, 3) void edge_mlp_kernel(
    const unsigned short* __restrict__ H, const int* __restrict__ pairs,
    const float* __restrict__ We1, const float* __restrict__ be1,
    const float* __restrict__ We2, const float* __restrict__ be2,
    float* __restrict__ out) {
  __shared__ uint4 wlds[1536];  // 24 frags x 64 lanes x 16B = 24 KB
  const int tid = threadIdx.x;

  // Stage We1^T A-frags into LDS (layout verified in round 2):
  // frag f=c*4+mt, entry ln: elem j = We1[(c*32+(ln>>4)*8+j)*64 + mt*16+(ln&15)]
  for (int s = tid; s < 1536; s += 256) {
    int f = s >> 6;
    int ln = s & 63;
    int c = f >> 2, mt = f & 3;
    int kb = c * 32 + (ln >> 4) * 8;
    int col = mt * 16 + (ln & 15);
    unsigned w0 = f2bf_rne(We1[(kb + 0) * 64 + col]) |
                  (f2bf_rne(We1[(kb + 1) * 64 + col]) << 16);
    unsigned w1 = f2bf_rne(We1[(kb + 2) * 64 + col]) |
                  (f2bf_rne(We1[(kb + 3) * 64 + col]) << 16);
    unsigned w2 = f2bf_rne(We1[(kb + 4) * 64 + col]) |
                  (f2bf_rne(We1[(kb + 5) * 64 + col]) << 16);
    unsigned w3 = f2bf_rne(We1[(kb + 6) * 64 + col]) |
                  (f2bf_rne(We1[(kb + 7) * 64 + col]) << 16);
    wlds[s] = make_uint4(w0, w1, w2, w3);
  }

  const int lane = tid & 63;
  const int l15 = lane & 15;
  const int quad = lane >> 4;

  // Per-lane epilogue constants: hidden unit u = mt*16 + quad*4 + r.
  float be1v[16], we2v[16];
#pragma unroll
  for (int mt = 0; mt < 4; ++mt)
#pragma unroll
    for (int r = 0; r < 4; ++r) {
      be1v[mt * 4 + r] = be1[mt * 16 + quad * 4 + r];
      we2v[mt * 4 + r] = We2[mt * 16 + quad * 4 + r];
    }
  const float be2v = be2[0];
  __syncthreads();

  const int wid = blockIdx.x * 4 + (tid >> 6);
  const int nw = gridDim.x * 4;
  const int ntiles = N_EDGES / 16;
  const int2* pairs2 = (const int2*)pairs;
  const uint4* wfrag = wlds + lane;  // frag f at wfrag[f*64]

  // Prologue: pairs for t0,t1; gathers for t0 in flight.
  int t1 = wid + nw;
  int2 uvA = pairs2[wid * 16 + l15];
  int2 uvB = pairs2[(t1 < ntiles ? t1 : wid) * 16 + l15];
  const uint4* pu = (const uint4*)(H + uvA.x * 64 + quad * 8);
  const uint4* pv = (const uint4*)(H + uvA.y * 64 + quad * 8);
  uint4 g0 = pu[0], g1 = pu[4], g2 = pv[0], g3 = pv[4];

  for (int tile = wid; tile < ntiles; tile += nw) {
    // Issue next tile's gathers (addresses ready since last iteration).
    const uint4* qu = (const uint4*)(H + uvB.x * 64 + quad * 8);
    const uint4* qv = (const uint4*)(H + uvB.y * 64 + quad * 8);
    uint4 n0 = qu[0], n1 = qu[4], n2 = qv[0], n3 = qv[4];
    int t2 = tile + 2 * nw;
    int2 uvC = pairs2[(t2 < ntiles ? t2 : tile) * 16 + l15];

    uint4 ab0, ab1;
    ab0.x = absdiff_pack(g0.x, g2.x);
    ab0.y = absdiff_pack(g0.y, g2.y);
    ab0.z = absdiff_pack(g0.z, g2.z);
    ab0.w = absdiff_pack(g0.w, g2.w);
    ab1.x = absdiff_pack(g1.x, g3.x);
    ab1.y = absdiff_pack(g1.y, g3.y);
    ab1.z = absdiff_pack(g1.z, g3.z);
    ab1.w = absdiff_pack(g1.w, g3.w);

    bf16x8 b[6];
    b[0] = __builtin_bit_cast(bf16x8, g0);
    b[1] = __builtin_bit_cast(bf16x8, g1);
    b[2] = __builtin_bit_cast(bf16x8, g2);
    b[3] = __builtin_bit_cast(bf16x8, g3);
    b[4] = __builtin_bit_cast(bf16x8, ab0);
    b[5] = __builtin_bit_cast(bf16x8, ab1);

    f32x4 acc[4];
#pragma unroll
    for (int mt = 0; mt < 4; ++mt) acc[mt] = (f32x4){0.f, 0.f, 0.f, 0.f};
#pragma unroll
    for (int c = 0; c < 6; ++c)
#pragma unroll
      for (int mt = 0; mt < 4; ++mt) {
        bf16x8 a = __builtin_bit_cast(bf16x8, wfrag[(c * 4 + mt) * 64]);
        acc[mt] =
            __builtin_amdgcn_mfma_f32_16x16x32_bf16(a, b[c], acc[mt], 0, 0, 0);
      }

    float s = 0.f;
#pragma unroll
    for (int mt = 0; mt < 4; ++mt)
#pragma unroll
      for (int r = 0; r < 4; ++r)
        s += fmaxf(acc[mt][r] + be1v[mt * 4 + r], 0.f) * we2v[mt * 4 + r];
    s += __shfl_xor(s, 16);
    s += __shfl_xor(s, 32);
    if (quad == 0) out[tile * 16 + l15] = s + be2v;

    g0 = n0;
    g1 = n1;
    g2 = n2;
    g3 = n3;
    uvB = uvC;
  }
}

extern "C" void kernel_launch(void* const* d_in, const int* in_sizes, int n_in,
                              void* d_out, int out_size, void* d_ws,
                              size_t ws_size, hipStream_t stream) {
  const float* X = (const float*)d_in[0];
  const int* pairs = (const int*)d_in[1];
  const float* W1 = (const float*)d_in[2];
  const float* b1 = (const float*)d_in[3];
  const float* W2 = (const float*)d_in[4];
  const float* b2 = (const float*)d_in[5];
  const float* We1 = (const float*)d_in[6];
  const float* be1 = (const float*)d_in[7];
  const float* We2 = (const float*)d_in[8];
  const float* be2 = (const float*)d_in[9];
  float* out = (float*)d_out;
  unsigned short* H = (unsigned short*)d_ws;  // 100000*64 bf16 = 12.8 MB

  node_mfma_kernel<<<1024, 64, 0, stream>>>(X, W1, b1, W2, b2, H);
  edge_mlp_kernel<<<1024, 256, 0, stream>>>(H, pairs, We1, be1, We2, be2, out);
}

// Round 6
// 219.060 us; speedup vs baseline: 1.2103x; 1.2103x over previous
//
#include <hip/hip_runtime.h>

#define N_NODES 100000
#define N_EDGES 2000000

typedef __bf16 bf16x8 __attribute__((ext_vector_type(8)));
typedef float f32x4 __attribute__((ext_vector_type(4)));

__device__ __forceinline__ unsigned f2bf_rne(float f) {
  unsigned u = __builtin_bit_cast(unsigned, f);
  u += 0x7FFFu + ((u >> 16) & 1u);
  return u >> 16;
}

// Pack two NON-NEGATIVE f32 into bf16x2, round-half-up (3 VALU for 2 elems).
__device__ __forceinline__ unsigned pack_rhu(float lo, float hi) {
  unsigned ulo = __builtin_bit_cast(unsigned, lo) + 0x8000u;
  unsigned uhi = __builtin_bit_cast(unsigned, hi) + 0x8000u;
  return __builtin_amdgcn_perm(uhi, ulo, 0x07060302u);
}

// |a-b| on a packed bf16 pair -> packed bf16 pair (~7 VALU).
__device__ __forceinline__ unsigned absdiff_pack(unsigned a, unsigned b) {
  float alo = __builtin_bit_cast(float, a << 16);
  float ahi = __builtin_bit_cast(float, a & 0xFFFF0000u);
  float blo = __builtin_bit_cast(float, b << 16);
  float bhi = __builtin_bit_cast(float, b & 0xFFFF0000u);
  return pack_rhu(fabsf(alo - blo), fabsf(ahi - bhi));
}

// ---------------------------------------------------------------------------
// Node MLP (round-4 structure, proven) + grid-stride zeroing of `out` so the
// edge kernel can accumulate with atomicAdd. Kernel-boundary ordering makes
// the zeroes visible device-wide before edge_mlp starts.
// ---------------------------------------------------------------------------
__global__ __launch_bounds__(64, 1) void node_mfma_kernel(
    const float* __restrict__ X, const float* __restrict__ W1,
    const float* __restrict__ b1, const float* __restrict__ W2,
    const float* __restrict__ b2, unsigned short* __restrict__ H,
    float* __restrict__ out) {
  // Zero the 2M-float output (float4 stores, ~8 iters/lane at 1024 blocks).
  {
    float4 z = {0.f, 0.f, 0.f, 0.f};
    float4* o4 = (float4*)out;
    for (int i = blockIdx.x * 64 + threadIdx.x; i < N_EDGES / 4;
         i += gridDim.x * 64)
      o4[i] = z;
  }

  const int lane = threadIdx.x;
  const int l15 = lane & 15;
  const int quad = lane >> 4;

  float w1v[2][4][8], b1v[2][8];
#pragma unroll
  for (int c = 0; c < 2; ++c)
#pragma unroll
    for (int j = 0; j < 8; ++j) {
      int col = c * 32 + quad * 8 + j;
      b1v[c][j] = b1[col];
#pragma unroll
      for (int d = 0; d < 4; ++d) w1v[c][d][j] = W1[d * 64 + col];
    }

  uint4 afr[2][4];
#pragma unroll
  for (int c = 0; c < 2; ++c)
#pragma unroll
    for (int mt = 0; mt < 4; ++mt) {
      unsigned w[4];
#pragma unroll
      for (int p = 0; p < 4; ++p) {
        int k = c * 32 + quad * 8 + 2 * p;
        unsigned lo = f2bf_rne(W2[k * 64 + mt * 16 + l15]);
        unsigned hi = f2bf_rne(W2[(k + 1) * 64 + mt * 16 + l15]);
        w[p] = lo | (hi << 16);
      }
      afr[c][mt] = make_uint4(w[0], w[1], w[2], w[3]);
    }
  float b2v[16];
#pragma unroll
  for (int mt = 0; mt < 4; ++mt)
#pragma unroll
    for (int r = 0; r < 4; ++r) b2v[mt * 4 + r] = b2[mt * 16 + quad * 4 + r];

  const int ntiles = N_NODES / 16;  // 6250
  for (int tile = blockIdx.x; tile < ntiles; tile += gridDim.x) {
    float4 xv = ((const float4*)X)[tile * 16 + l15];

    uint4 bfr[2];
#pragma unroll
    for (int c = 0; c < 2; ++c) {
      unsigned w[4];
#pragma unroll
      for (int p = 0; p < 4; ++p) {
        float h0 = fmaxf(b1v[c][2 * p] + xv.x * w1v[c][0][2 * p] +
                             xv.y * w1v[c][1][2 * p] + xv.z * w1v[c][2][2 * p] +
                             xv.w * w1v[c][3][2 * p],
                         0.f);
        float h1 = fmaxf(b1v[c][2 * p + 1] + xv.x * w1v[c][0][2 * p + 1] +
                             xv.y * w1v[c][1][2 * p + 1] +
                             xv.z * w1v[c][2][2 * p + 1] +
                             xv.w * w1v[c][3][2 * p + 1],
                         0.f);
        w[p] = pack_rhu(h0, h1);
      }
      bfr[c] = make_uint4(w[0], w[1], w[2], w[3]);
    }

    f32x4 acc[4];
#pragma unroll
    for (int mt = 0; mt < 4; ++mt) acc[mt] = (f32x4){0.f, 0.f, 0.f, 0.f};
#pragma unroll
    for (int c = 0; c < 2; ++c)
#pragma unroll
      for (int mt = 0; mt < 4; ++mt)
        acc[mt] = __builtin_amdgcn_mfma_f32_16x16x32_bf16(
            __builtin_bit_cast(bf16x8, afr[c][mt]),
            __builtin_bit_cast(bf16x8, bfr[c]), acc[mt], 0, 0, 0);

    unsigned short* hrow = H + (tile * 16 + l15) * 64;
#pragma unroll
    for (int mt = 0; mt < 4; ++mt) {
      unsigned lo = pack_rhu(fmaxf(acc[mt][0] + b2v[mt * 4 + 0], 0.f),
                             fmaxf(acc[mt][1] + b2v[mt * 4 + 1], 0.f));
      unsigned hi = pack_rhu(fmaxf(acc[mt][2] + b2v[mt * 4 + 2], 0.f),
                             fmaxf(acc[mt][3] + b2v[mt * 4 + 3], 0.f));
      *(uint2*)(hrow + mt * 16 + quad * 4) = make_uint2(lo, hi);
    }
  }
}

// ---------------------------------------------------------------------------
// Edge MLP, mt-split wave pairs. Each wave owns HALF the 64 hidden units:
// afr = 6 chunks x 2 mt = 48 regs (AGPR side) + acc 8 -> AGPR ~56; arch side
// (gathers 32 + addr/epi ~40) ~75 — both fit the ~85/85 per-side budget at
// 3 waves/SIMD (rounds 2/5 showed any side exceeding its cap spills to
// scratch and thrashes L2; rounds 3/4 at 2 waves/SIMD were latency-bound at
// 1.8 TB/s << all BW ceilings -> more waves is the fix).
// ReLU is per-hidden-unit, so each wave computes its partial layer-2 dot
// AFTER the nonlinearity; the two halves combine via one atomicAdd per edge
// (out zeroed by node kernel) — no LDS exchange, no barrier (a barrier would
// drain vmcnt and kill the gather prefetch). Same-block wave pairs walk the
// same tile sequence so the duplicated row gathers mostly hit L1/L2.
// ---------------------------------------------------------------------------
__global__ __launch_bounds__(256, 3) void edge_mlp_kernel(
    const unsigned short* __restrict__ H, const int* __restrict__ pairs,
    const float* __restrict__ We1, const float* __restrict__ be1,
    const float* __restrict__ We2, const float* __restrict__ be2,
    float* __restrict__ out) {
  const int tid = threadIdx.x;
  const int lane = tid & 63;
  const int l15 = lane & 15;
  const int quad = lane >> 4;
  const int mth = (tid >> 6) & 1;  // which half of the 64 hidden units

  // We1^T A-frags for this wave's 2 mt tiles (global mt = mth*2 + jt).
  uint4 afr[6][2];
#pragma unroll
  for (int c = 0; c < 6; ++c)
#pragma unroll
    for (int jt = 0; jt < 2; ++jt) {
      int col = (mth * 2 + jt) * 16 + l15;
      unsigned w[4];
#pragma unroll
      for (int p = 0; p < 4; ++p) {
        int k = c * 32 + quad * 8 + 2 * p;
        unsigned lo = f2bf_rne(We1[k * 64 + col]);
        unsigned hi = f2bf_rne(We1[(k + 1) * 64 + col]);
        w[p] = lo | (hi << 16);
      }
      afr[c][jt] = make_uint4(w[0], w[1], w[2], w[3]);
    }
  float be1v[8], we2v[8];
#pragma unroll
  for (int jt = 0; jt < 2; ++jt)
#pragma unroll
    for (int r = 0; r < 4; ++r) {
      int row = (mth * 2 + jt) * 16 + quad * 4 + r;
      be1v[jt * 4 + r] = be1[row];
      we2v[jt * 4 + r] = We2[row];
    }
  const float be2h = (mth == 0) ? be2[0] : 0.f;

  // Wave pair (tid>>7) of each block shares a tile sequence.
  const int pid = blockIdx.x * 2 + (tid >> 7);
  const int np = gridDim.x * 2;
  const int ntiles = N_EDGES / 16;
  const int2* pairs2 = (const int2*)pairs;

  // Prologue: pairs for t0,t1; gathers for t0 in flight.
  int t1 = pid + np;
  int2 uvA = pairs2[pid * 16 + l15];
  int2 uvB = pairs2[(t1 < ntiles ? t1 : pid) * 16 + l15];
  const uint4* pu = (const uint4*)(H + uvA.x * 64 + quad * 8);
  const uint4* pv = (const uint4*)(H + uvA.y * 64 + quad * 8);
  uint4 g0 = pu[0], g1 = pu[4], g2 = pv[0], g3 = pv[4];

  for (int tile = pid; tile < ntiles; tile += np) {
    // Issue next tile's gathers (addresses ready since last iteration).
    const uint4* qu = (const uint4*)(H + uvB.x * 64 + quad * 8);
    const uint4* qv = (const uint4*)(H + uvB.y * 64 + quad * 8);
    uint4 n0 = qu[0], n1 = qu[4], n2 = qv[0], n3 = qv[4];
    int t2 = tile + 2 * np;
    int2 uvC = pairs2[(t2 < ntiles ? t2 : tile) * 16 + l15];

    uint4 ab0, ab1;
    ab0.x = absdiff_pack(g0.x, g2.x);
    ab0.y = absdiff_pack(g0.y, g2.y);
    ab0.z = absdiff_pack(g0.z, g2.z);
    ab0.w = absdiff_pack(g0.w, g2.w);
    ab1.x = absdiff_pack(g1.x, g3.x);
    ab1.y = absdiff_pack(g1.y, g3.y);
    ab1.z = absdiff_pack(g1.z, g3.z);
    ab1.w = absdiff_pack(g1.w, g3.w);

    bf16x8 b[6];
    b[0] = __builtin_bit_cast(bf16x8, g0);
    b[1] = __builtin_bit_cast(bf16x8, g1);
    b[2] = __builtin_bit_cast(bf16x8, g2);
    b[3] = __builtin_bit_cast(bf16x8, g3);
    b[4] = __builtin_bit_cast(bf16x8, ab0);
    b[5] = __builtin_bit_cast(bf16x8, ab1);

    f32x4 acc[2];
    acc[0] = (f32x4){0.f, 0.f, 0.f, 0.f};
    acc[1] = (f32x4){0.f, 0.f, 0.f, 0.f};
#pragma unroll
    for (int c = 0; c < 6; ++c)
#pragma unroll
      for (int jt = 0; jt < 2; ++jt)
        acc[jt] = __builtin_amdgcn_mfma_f32_16x16x32_bf16(
            __builtin_bit_cast(bf16x8, afr[c][jt]), b[c], acc[jt], 0, 0, 0);

    // Partial layer-2 dot over this wave's 32 hidden units (post-ReLU, so
    // halves add linearly), reduce across quads, one atomicAdd per edge.
    float s = 0.f;
#pragma unroll
    for (int jt = 0; jt < 2; ++jt)
#pragma unroll
      for (int r = 0; r < 4; ++r)
        s += fmaxf(acc[jt][r] + be1v[jt * 4 + r], 0.f) * we2v[jt * 4 + r];
    s += __shfl_xor(s, 16);
    s += __shfl_xor(s, 32);
    if (quad == 0) atomicAdd(&out[tile * 16 + l15], s + be2h);

    g0 = n0;
    g1 = n1;
    g2 = n2;
    g3 = n3;
    uvB = uvC;
  }
}

extern "C" void kernel_launch(void* const* d_in, const int* in_sizes, int n_in,
                              void* d_out, int out_size, void* d_ws,
                              size_t ws_size, hipStream_t stream) {
  const float* X = (const float*)d_in[0];
  const int* pairs = (const int*)d_in[1];
  const float* W1 = (const float*)d_in[2];
  const float* b1 = (const float*)d_in[3];
  const float* W2 = (const float*)d_in[4];
  const float* b2 = (const float*)d_in[5];
  const float* We1 = (const float*)d_in[6];
  const float* be1 = (const float*)d_in[7];
  const float* We2 = (const float*)d_in[8];
  const float* be2 = (const float*)d_in[9];
  float* out = (float*)d_out;
  unsigned short* H = (unsigned short*)d_ws;  // 100000*64 bf16 = 12.8 MB

  node_mfma_kernel<<<1024, 64, 0, stream>>>(X, W1, b1, W2, b2, H, out);
  // 768 = 3 blocks/CU x 256 CU -> exactly the 3-waves/SIMD residency.
  edge_mlp_kernel<<<768, 256, 0, stream>>>(H, pairs, We1, be1, We2, be2, out);
}

// Round 7
// 168.561 us; speedup vs baseline: 1.5729x; 1.2996x over previous
//
#include <hip/hip_runtime.h>

#define N_NODES 100000
#define N_EDGES 2000000

typedef __bf16 bf16x8 __attribute__((ext_vector_type(8)));
typedef float f32x4 __attribute__((ext_vector_type(4)));

__device__ __forceinline__ unsigned f2bf_rne(float f) {
  unsigned u = __builtin_bit_cast(unsigned, f);
  u += 0x7FFFu + ((u >> 16) & 1u);
  return u >> 16;
}

// Pack two NON-NEGATIVE f32 into bf16x2, round-half-up (3 VALU for 2 elems).
__device__ __forceinline__ unsigned pack_rhu(float lo, float hi) {
  unsigned ulo = __builtin_bit_cast(unsigned, lo) + 0x8000u;
  unsigned uhi = __builtin_bit_cast(unsigned, hi) + 0x8000u;
  return __builtin_amdgcn_perm(uhi, ulo, 0x07060302u);
}

// |a-b| on a packed bf16 pair -> packed bf16 pair.
__device__ __forceinline__ unsigned absdiff_pack(unsigned a, unsigned b) {
  float alo = __builtin_bit_cast(float, a << 16);
  float ahi = __builtin_bit_cast(float, a & 0xFFFF0000u);
  float blo = __builtin_bit_cast(float, b << 16);
  float bhi = __builtin_bit_cast(float, b & 0xFFFF0000u);
  return pack_rhu(fabsf(alo - blo), fabsf(ahi - bhi));
}

// ---------------------------------------------------------------------------
// Node MLP via MFMA, grid-stride (round-4 version, proven). The constant
// ~77us total-minus-edge gap across 4 different node configs is fixed
// harness overhead, not this kernel — leave it alone.
// ---------------------------------------------------------------------------
__global__ __launch_bounds__(64, 1) void node_mfma_kernel(
    const float* __restrict__ X, const float* __restrict__ W1,
    const float* __restrict__ b1, const float* __restrict__ W2,
    const float* __restrict__ b2, unsigned short* __restrict__ H) {
  const int lane = threadIdx.x;
  const int l15 = lane & 15;
  const int quad = lane >> 4;

  float w1v[2][4][8], b1v[2][8];
#pragma unroll
  for (int c = 0; c < 2; ++c)
#pragma unroll
    for (int j = 0; j < 8; ++j) {
      int col = c * 32 + quad * 8 + j;
      b1v[c][j] = b1[col];
#pragma unroll
      for (int d = 0; d < 4; ++d) w1v[c][d][j] = W1[d * 64 + col];
    }

  uint4 afr[2][4];
#pragma unroll
  for (int c = 0; c < 2; ++c)
#pragma unroll
    for (int mt = 0; mt < 4; ++mt) {
      unsigned w[4];
#pragma unroll
      for (int p = 0; p < 4; ++p) {
        int k = c * 32 + quad * 8 + 2 * p;
        unsigned lo = f2bf_rne(W2[k * 64 + mt * 16 + l15]);
        unsigned hi = f2bf_rne(W2[(k + 1) * 64 + mt * 16 + l15]);
        w[p] = lo | (hi << 16);
      }
      afr[c][mt] = make_uint4(w[0], w[1], w[2], w[3]);
    }
  float b2v[16];
#pragma unroll
  for (int mt = 0; mt < 4; ++mt)
#pragma unroll
    for (int r = 0; r < 4; ++r) b2v[mt * 4 + r] = b2[mt * 16 + quad * 4 + r];

  const int ntiles = N_NODES / 16;  // 6250
  for (int tile = blockIdx.x; tile < ntiles; tile += gridDim.x) {
    float4 xv = ((const float4*)X)[tile * 16 + l15];

    uint4 bfr[2];
#pragma unroll
    for (int c = 0; c < 2; ++c) {
      unsigned w[4];
#pragma unroll
      for (int p = 0; p < 4; ++p) {
        float h0 = fmaxf(b1v[c][2 * p] + xv.x * w1v[c][0][2 * p] +
                             xv.y * w1v[c][1][2 * p] + xv.z * w1v[c][2][2 * p] +
                             xv.w * w1v[c][3][2 * p],
                         0.f);
        float h1 = fmaxf(b1v[c][2 * p + 1] + xv.x * w1v[c][0][2 * p + 1] +
                             xv.y * w1v[c][1][2 * p + 1] +
                             xv.z * w1v[c][2][2 * p + 1] +
                             xv.w * w1v[c][3][2 * p + 1],
                         0.f);
        w[p] = pack_rhu(h0, h1);
      }
      bfr[c] = make_uint4(w[0], w[1], w[2], w[3]);
    }

    f32x4 acc[4];
#pragma unroll
    for (int mt = 0; mt < 4; ++mt) acc[mt] = (f32x4){0.f, 0.f, 0.f, 0.f};
#pragma unroll
    for (int c = 0; c < 2; ++c)
#pragma unroll
      for (int mt = 0; mt < 4; ++mt)
        acc[mt] = __builtin_amdgcn_mfma_f32_16x16x32_bf16(
            __builtin_bit_cast(bf16x8, afr[c][mt]),
            __builtin_bit_cast(bf16x8, bfr[c]), acc[mt], 0, 0, 0);

    unsigned short* hrow = H + (tile * 16 + l15) * 64;
#pragma unroll
    for (int mt = 0; mt < 4; ++mt) {
      unsigned lo = pack_rhu(fmaxf(acc[mt][0] + b2v[mt * 4 + 0], 0.f),
                             fmaxf(acc[mt][1] + b2v[mt * 4 + 1], 0.f));
      unsigned hi = pack_rhu(fmaxf(acc[mt][2] + b2v[mt * 4 + 2], 0.f),
                             fmaxf(acc[mt][3] + b2v[mt * 4 + 3], 0.f));
      *(uint2*)(hrow + mt * 16 + quad * 4) = make_uint2(lo, hi);
    }
  }
}

// ---------------------------------------------------------------------------
// Edge MLP: round-3 structure (full 24-frag We1^T in registers/AGPRs, one
// wave per 16-edge tile, no atomics) + TRUE 2-deep gather pipeline:
// 3 static buffers, loop unrolled by 3, refill loads written DIRECTLY into
// the buffer just consumed (WAR only — no rotation copies, which in round 4
// forced a same-iteration vmcnt wait and collapsed the pipeline to 1-deep).
// Buffer k is waited on 2 full tile-computes after its refill was issued,
// covering the ~400-600cyc L3-serve gather latency (H=12.8MB >> 4MB L2/XCD,
// FETCH 183MB is L2-miss traffic). Arch ~125 + AGPR ~112 = ~237 <= 256 ->
// fits (256,2) without spill (min-waves=3 crushes arch regs to 64-84 and
// spills — rounds 5/6).
// ---------------------------------------------------------------------------
__global__ __launch_bounds__(256, 2) void edge_mlp_kernel(
    const unsigned short* __restrict__ H, const int* __restrict__ pairs,
    const float* __restrict__ We1, const float* __restrict__ be1,
    const float* __restrict__ We2, const float* __restrict__ be2,
    float* __restrict__ out) {
  const int tid = threadIdx.x;
  const int lane = tid & 63;
  const int l15 = lane & 15;
  const int quad = lane >> 4;

  // Persistent We1^T A-frags (96 regs, AGPR side of the unified file).
  uint4 afr[6][4];
#pragma unroll
  for (int c = 0; c < 6; ++c)
#pragma unroll
    for (int mt = 0; mt < 4; ++mt) {
      unsigned w[4];
#pragma unroll
      for (int p = 0; p < 4; ++p) {
        int k = c * 32 + quad * 8 + 2 * p;
        unsigned lo = f2bf_rne(We1[k * 64 + mt * 16 + l15]);
        unsigned hi = f2bf_rne(We1[(k + 1) * 64 + mt * 16 + l15]);
        w[p] = lo | (hi << 16);
      }
      afr[c][mt] = make_uint4(w[0], w[1], w[2], w[3]);
    }
  float be1v[16], we2v[16];
#pragma unroll
  for (int mt = 0; mt < 4; ++mt)
#pragma unroll
    for (int r = 0; r < 4; ++r) {
      be1v[mt * 4 + r] = be1[mt * 16 + quad * 4 + r];
      we2v[mt * 4 + r] = We2[mt * 16 + quad * 4 + r];
    }
  const float be2v = be2[0];

  const int wid = blockIdx.x * 4 + (tid >> 6);
  const int nw = gridDim.x * 4;
  const int ntiles = N_EDGES / 16;
  const int last = ntiles - 1;
  const int2* pairs2 = (const int2*)pairs;

  // 3 gather buffers + next-pair registers, loaded for tiles wid+{0,1,2}*nw.
  uint4 g[3][4];
  int2 uvn[3];
#pragma unroll
  for (int k = 0; k < 3; ++k) {
    int t = wid + k * nw;
    int2 uv = pairs2[(t <= last ? t : last) * 16 + l15];
    const uint4* pu = (const uint4*)(H + uv.x * 64 + quad * 8);
    const uint4* pv = (const uint4*)(H + uv.y * 64 + quad * 8);
    g[k][0] = pu[0];
    g[k][1] = pu[4];
    g[k][2] = pv[0];
    g[k][3] = pv[4];
    int tn = t + 3 * nw;
    uvn[k] = pairs2[(tn <= last ? tn : last) * 16 + l15];
  }

  for (int base = wid; base < ntiles; base += 3 * nw) {
#pragma unroll
    for (int k = 0; k < 3; ++k) {
      const int t = base + k * nw;

      // ---- consume buffer k (loads issued 2 tile-computes ago) ----
      uint4 ab0, ab1;
      ab0.x = absdiff_pack(g[k][0].x, g[k][2].x);
      ab0.y = absdiff_pack(g[k][0].y, g[k][2].y);
      ab0.z = absdiff_pack(g[k][0].z, g[k][2].z);
      ab0.w = absdiff_pack(g[k][0].w, g[k][2].w);
      ab1.x = absdiff_pack(g[k][1].x, g[k][3].x);
      ab1.y = absdiff_pack(g[k][1].y, g[k][3].y);
      ab1.z = absdiff_pack(g[k][1].z, g[k][3].z);
      ab1.w = absdiff_pack(g[k][1].w, g[k][3].w);

      bf16x8 b[6];
      b[0] = __builtin_bit_cast(bf16x8, g[k][0]);
      b[1] = __builtin_bit_cast(bf16x8, g[k][1]);
      b[2] = __builtin_bit_cast(bf16x8, g[k][2]);
      b[3] = __builtin_bit_cast(bf16x8, g[k][3]);
      b[4] = __builtin_bit_cast(bf16x8, ab0);
      b[5] = __builtin_bit_cast(bf16x8, ab1);

      f32x4 acc[4];
#pragma unroll
      for (int mt = 0; mt < 4; ++mt) acc[mt] = (f32x4){0.f, 0.f, 0.f, 0.f};
#pragma unroll
      for (int c = 0; c < 6; ++c)
#pragma unroll
        for (int mt = 0; mt < 4; ++mt)
          acc[mt] = __builtin_amdgcn_mfma_f32_16x16x32_bf16(
              __builtin_bit_cast(bf16x8, afr[c][mt]), b[c], acc[mt], 0, 0, 0);

      // ---- refill buffer k for tile t+3nw (WAR on g[k]: no wait) ----
      {
        const uint4* qu = (const uint4*)(H + uvn[k].x * 64 + quad * 8);
        const uint4* qv = (const uint4*)(H + uvn[k].y * 64 + quad * 8);
        g[k][0] = qu[0];
        g[k][1] = qu[4];
        g[k][2] = qv[0];
        g[k][3] = qv[4];
        int tn = t + 6 * nw;
        uvn[k] = pairs2[(tn <= last ? tn : last) * 16 + l15];
      }

      // ---- epilogue (uses only acc, independent of refill) ----
      float s = 0.f;
#pragma unroll
      for (int mt = 0; mt < 4; ++mt)
#pragma unroll
        for (int r = 0; r < 4; ++r)
          s += fmaxf(acc[mt][r] + be1v[mt * 4 + r], 0.f) * we2v[mt * 4 + r];
      s += __shfl_xor(s, 16);
      s += __shfl_xor(s, 32);
      if (quad == 0 && t <= last) out[t * 16 + l15] = s + be2v;
    }
  }
}

extern "C" void kernel_launch(void* const* d_in, const int* in_sizes, int n_in,
                              void* d_out, int out_size, void* d_ws,
                              size_t ws_size, hipStream_t stream) {
  const float* X = (const float*)d_in[0];
  const int* pairs = (const int*)d_in[1];
  const float* W1 = (const float*)d_in[2];
  const float* b1 = (const float*)d_in[3];
  const float* W2 = (const float*)d_in[4];
  const float* b2 = (const float*)d_in[5];
  const float* We1 = (const float*)d_in[6];
  const float* be1 = (const float*)d_in[7];
  const float* We2 = (const float*)d_in[8];
  const float* be2 = (const float*)d_in[9];
  float* out = (float*)d_out;
  unsigned short* H = (unsigned short*)d_ws;  // 100000*64 bf16 = 12.8 MB

  node_mfma_kernel<<<1024, 64, 0, stream>>>(X, W1, b1, W2, b2, H);
  edge_mlp_kernel<<<1024, 256, 0, stream>>>(H, pairs, We1, be1, We2, be2, out);
}